// Round 7
// baseline (157.183 us; speedup 1.0000x reference)
//
#include <hip/hip_runtime.h>
#include <hip/hip_fp16.h>

#define NSITES 262144

struct alignas(16) H8 { __half2 h[4]; };   // 8 fp16 values = 16 B
typedef __attribute__((ext_vector_type(2))) float floatx2;
typedef __attribute__((ext_vector_type(4))) unsigned int uintx4;

// ws layout:
//   G8 [NSITES][32] fp8 e4m3, site-major, 32 B/site   (8 MiB)   j = b*8+o
//   Sp [NSITES][32] fp16, site-major, 64 B/site       (16 MiB)

__global__ __launch_bounds__(256) void prep_kernel(
    const float* __restrict__ In,       // [4][8][NSITES]
    const float* __restrict__ Weights,  // [8][8][16]
    const float* __restrict__ bias,     // [8][8]
    uint2* __restrict__ G8,             // [NSITES][4] quads of 8 fp8
    H8*    __restrict__ Sp)             // [NSITES][4]
{
    __shared__ float ws[8][8], wn[8][8], be[8];
    int t = threadIdx.x;
    if (t < 64) {
        int o = t >> 3, k = t & 7;
        float s0 = 0.f, s1 = 0.f;
        #pragma unroll
        for (int s = 0; s < 8; ++s) {
            s0 += Weights[s*128 + o*16 + k];
            s1 += Weights[s*128 + o*16 + 8 + k];
        }
        ws[o][k] = s0; wn[o][k] = s1;
    } else if (t < 72) {
        int o = t - 64;
        float s = 0.f;
        #pragma unroll
        for (int q = 0; q < 8; ++q) s += bias[q*8 + o];
        be[o] = s;
    }
    __syncthreads();

    int site = blockIdx.x * 256 + t;
    float x[4][8];
    #pragma unroll
    for (int b = 0; b < 4; ++b)
        #pragma unroll
        for (int i = 0; i < 8; ++i)
            x[b][i] = In[(b*8 + i) * NSITES + site];   // coalesced

    #pragma unroll
    for (int b = 0; b < 4; ++b) {          // quad q == b (8 comps per quad)
        float g[8], s[8];
        #pragma unroll
        for (int o = 0; o < 8; ++o) {
            float a0 = 0.f, a1 = be[o];
            #pragma unroll
            for (int i = 0; i < 8; ++i) {
                a0 = fmaf(wn[o][i], x[b][i], a0);
                a1 = fmaf(ws[o][i], x[b][i], a1);
            }
            g[o] = a0; s[o] = a1;
        }
        unsigned int w0 = 0, w1 = 0;
        w0 = __builtin_amdgcn_cvt_pk_fp8_f32(g[0], g[1], w0, false);
        w0 = __builtin_amdgcn_cvt_pk_fp8_f32(g[2], g[3], w0, true);
        w1 = __builtin_amdgcn_cvt_pk_fp8_f32(g[4], g[5], w1, false);
        w1 = __builtin_amdgcn_cvt_pk_fp8_f32(g[6], g[7], w1, true);
        G8[site*4 + b] = make_uint2(w0, w1);

        H8 sv;
        #pragma unroll
        for (int p = 0; p < 4; ++p) sv.h[p] = __floats2half2_rn(s[2*p], s[2*p+1]);
        Sp[site*4 + b] = sv;
    }
}

// 4 lanes per site; lane owns 8 comps. G record = 32 B fp8, gather load = 8 B/lane.
__global__ __launch_bounds__(256) void gather_kernel(
    const H8*    __restrict__ Sp,
    const uint2* __restrict__ G8,
    const int*   __restrict__ NN,    // [13][NSITES], rows 1..12 used
    float*       __restrict__ out)   // [32][NSITES]
{
    __shared__ float lds[32][65];
    int t    = threadIdx.x;        // 256
    int q    = t & 3;              // which 8-comp chunk
    int sl   = t >> 2;             // local site 0..63
    int base = blockIdx.x * 64;
    int n    = base + sl;

    // streaming (nt) load of Sp quad -> 8 floats
    uintx4 spw = __builtin_nontemporal_load((const uintx4*)Sp + (n*4 + q));
    float sp[8];
    #pragma unroll
    for (int p = 0; p < 4; ++p) {
        unsigned int w = spw[p];
        __half2 h; __builtin_memcpy(&h, &w, 4);
        float2 f = __half22float2(h);
        sp[2*p] = f.x; sp[2*p+1] = f.y;
    }

    const float NLOG2E = -1.44269504f;
    float acc[8], prod[8];
    #pragma unroll
    for (int k = 0; k < 8; ++k) { acc[k] = 0.f; prod[k] = 1.f; }

    #pragma unroll
    for (int z = 1; z < 13; ++z) {
        int m = __builtin_nontemporal_load(&NN[z * NSITES + n]);
        uint2 gw = G8[m*4 + q];            // cached: keep G in L2
        float g[8];
        floatx2 p;
        p = __builtin_amdgcn_cvt_pk_f32_fp8(gw.x, false); g[0]=p[0]; g[1]=p[1];
        p = __builtin_amdgcn_cvt_pk_f32_fp8(gw.x, true ); g[2]=p[0]; g[3]=p[1];
        p = __builtin_amdgcn_cvt_pk_f32_fp8(gw.y, false); g[4]=p[0]; g[5]=p[1];
        p = __builtin_amdgcn_cvt_pk_f32_fp8(gw.y, true ); g[6]=p[0]; g[7]=p[1];
        #pragma unroll
        for (int k = 0; k < 8; ++k) {
            float x  = sp[k] + g[k];
            float ax = fabsf(x);
            acc[k] += fmaxf(x, 0.f);
            float e = __builtin_amdgcn_exp2f(ax * NLOG2E);  // e^-|x|
            prod[k] = fmaf(prod[k], e, prod[k]);            // Π (1+e^-|x|)  (≤ 2^12)
        }
    }

    #pragma unroll
    for (int k = 0; k < 8; ++k)
        lds[q*8 + k][sl] = acc[k] + 0.69314718f * __builtin_amdgcn_logf(prod[k]);
    __syncthreads();

    int s  = t & 63;
    int j0 = t >> 6;                     // 0..3
    #pragma unroll
    for (int r = 0; r < 8; ++r) {
        int j = j0*8 + r;
        __builtin_nontemporal_store(lds[j][s], &out[j * NSITES + base + s]);
    }
}

extern "C" void kernel_launch(void* const* d_in, const int* in_sizes, int n_in,
                              void* d_out, int out_size, void* d_ws, size_t ws_size,
                              hipStream_t stream) {
    const float* In      = (const float*)d_in[0];
    const int*   NN      = (const int*)  d_in[1];
    const float* Weights = (const float*)d_in[2];
    const float* bias    = (const float*)d_in[3];
    float* out = (float*)d_out;

    uint2* G8 = (uint2*)d_ws;                             // 8 MiB
    H8*    Sp = (H8*)((char*)d_ws + (size_t)NSITES * 32); // 16 MiB

    prep_kernel<<<NSITES / 256, 256, 0, stream>>>(In, Weights, bias, G8, Sp);
    gather_kernel<<<NSITES / 64, 256, 0, stream>>>(Sp, G8, NN, out);
}

// Round 8
// 133.531 us; speedup vs baseline: 1.1771x; 1.1771x over previous
//
#include <hip/hip_runtime.h>
#include <hip/hip_fp16.h>

#define NSITES 262144

struct alignas(16) H8 { __half2 h[4]; };   // 8 fp16 values = 16 B
typedef __attribute__((ext_vector_type(2))) float floatx2;
typedef __attribute__((ext_vector_type(4))) unsigned int uintx4;

// ws layout:
//   G8 [NSITES][32] fp8 e4m3, site-major, 32 B/site   (8 MiB)   j = b*8+o
//   Sp [NSITES][32] fp16, site-major, 64 B/site       (16 MiB)

// One thread per (site, batch). Lane order b=t&3 -> stores are lane-consecutive.
__global__ __launch_bounds__(256) void prep_kernel(
    const float* __restrict__ In,       // [4][8][NSITES]
    const float* __restrict__ Weights,  // [8][8][16]
    const float* __restrict__ bias,     // [8][8]
    uint2* __restrict__ G8,             // [NSITES][4] quads of 8 fp8
    H8*    __restrict__ Sp)             // [NSITES][4]
{
    __shared__ float ws[8][8], wn[8][8], be[8];
    int t = threadIdx.x;
    if (t < 64) {
        int o = t >> 3, k = t & 7;
        float s0 = 0.f, s1 = 0.f;
        #pragma unroll
        for (int s = 0; s < 8; ++s) {
            s0 += Weights[s*128 + o*16 + k];
            s1 += Weights[s*128 + o*16 + 8 + k];
        }
        ws[o][k] = s0; wn[o][k] = s1;
    } else if (t < 72) {
        int o = t - 64;
        float s = 0.f;
        #pragma unroll
        for (int q = 0; q < 8; ++q) s += bias[q*8 + o];
        be[o] = s;
    }
    __syncthreads();

    int b    = t & 3;                    // batch (= quad index)
    int sl   = t >> 2;                   // 0..63
    int site = blockIdx.x * 64 + sl;

    float x[8];
    #pragma unroll
    for (int i = 0; i < 8; ++i)
        x[i] = In[(b*8 + i) * NSITES + site];   // 4×64B segments per wave-load

    float g[8], s[8];
    #pragma unroll
    for (int o = 0; o < 8; ++o) {
        float a0 = 0.f, a1 = be[o];
        #pragma unroll
        for (int i = 0; i < 8; ++i) {
            a0 = fmaf(wn[o][i], x[i], a0);
            a1 = fmaf(ws[o][i], x[i], a1);
        }
        g[o] = a0; s[o] = a1;
    }

    unsigned int w0 = 0, w1 = 0;
    w0 = __builtin_amdgcn_cvt_pk_fp8_f32(g[0], g[1], w0, false);
    w0 = __builtin_amdgcn_cvt_pk_fp8_f32(g[2], g[3], w0, true);
    w1 = __builtin_amdgcn_cvt_pk_fp8_f32(g[4], g[5], w1, false);
    w1 = __builtin_amdgcn_cvt_pk_fp8_f32(g[6], g[7], w1, true);
    G8[site*4 + b] = make_uint2(w0, w1);        // lane-consecutive 8B -> 512B/inst

    H8 sv;
    #pragma unroll
    for (int p = 0; p < 4; ++p) sv.h[p] = __floats2half2_rn(s[2*p], s[2*p+1]);
    Sp[site*4 + b] = sv;                        // lane-consecutive 16B -> 1KB/inst
}

// 4 lanes per site; lane owns 8 comps. G record = 32 B fp8, gather load = 8 B/lane.
__global__ __launch_bounds__(256) void gather_kernel(
    const H8*    __restrict__ Sp,
    const uint2* __restrict__ G8,
    const int*   __restrict__ NN,    // [13][NSITES], rows 1..12 used
    float*       __restrict__ out)   // [32][NSITES]
{
    __shared__ float lds[32][65];
    int t    = threadIdx.x;        // 256
    int q    = t & 3;              // which 8-comp chunk
    int sl   = t >> 2;             // local site 0..63
    int base = blockIdx.x * 64;
    int n    = base + sl;

    // streaming (nt) load of Sp quad -> 8 floats
    uintx4 spw = __builtin_nontemporal_load((const uintx4*)Sp + (n*4 + q));
    float sp[8];
    #pragma unroll
    for (int p = 0; p < 4; ++p) {
        unsigned int w = spw[p];
        __half2 h; __builtin_memcpy(&h, &w, 4);
        float2 f = __half22float2(h);
        sp[2*p] = f.x; sp[2*p+1] = f.y;
    }

    const float NLOG2E = -1.44269504f;
    float acc[8], prod[8];
    #pragma unroll
    for (int k = 0; k < 8; ++k) { acc[k] = 0.f; prod[k] = 1.f; }

    #pragma unroll
    for (int z = 1; z < 13; ++z) {
        int m = __builtin_nontemporal_load(&NN[z * NSITES + n]);
        uint2 gw = G8[m*4 + q];            // cached: keep G in L2
        float g[8];
        floatx2 p;
        p = __builtin_amdgcn_cvt_pk_f32_fp8(gw.x, false); g[0]=p[0]; g[1]=p[1];
        p = __builtin_amdgcn_cvt_pk_f32_fp8(gw.x, true ); g[2]=p[0]; g[3]=p[1];
        p = __builtin_amdgcn_cvt_pk_f32_fp8(gw.y, false); g[4]=p[0]; g[5]=p[1];
        p = __builtin_amdgcn_cvt_pk_f32_fp8(gw.y, true ); g[6]=p[0]; g[7]=p[1];
        #pragma unroll
        for (int k = 0; k < 8; ++k) {
            float x  = sp[k] + g[k];
            float ax = fabsf(x);
            acc[k] += fmaxf(x, 0.f);
            float e = __builtin_amdgcn_exp2f(ax * NLOG2E);  // e^-|x|
            prod[k] = fmaf(prod[k], e, prod[k]);            // Π (1+e^-|x|)  (≤ 2^12)
        }
    }

    #pragma unroll
    for (int k = 0; k < 8; ++k)
        lds[q*8 + k][sl] = acc[k] + 0.69314718f * __builtin_amdgcn_logf(prod[k]);
    __syncthreads();

    int s  = t & 63;
    int j0 = t >> 6;                     // 0..3
    #pragma unroll
    for (int r = 0; r < 8; ++r) {
        int j = j0*8 + r;
        __builtin_nontemporal_store(lds[j][s], &out[j * NSITES + base + s]);
    }
}

extern "C" void kernel_launch(void* const* d_in, const int* in_sizes, int n_in,
                              void* d_out, int out_size, void* d_ws, size_t ws_size,
                              hipStream_t stream) {
    const float* In      = (const float*)d_in[0];
    const int*   NN      = (const int*)  d_in[1];
    const float* Weights = (const float*)d_in[2];
    const float* bias    = (const float*)d_in[3];
    float* out = (float*)d_out;

    uint2* G8 = (uint2*)d_ws;                             // 8 MiB
    H8*    Sp = (H8*)((char*)d_ws + (size_t)NSITES * 32); // 16 MiB

    prep_kernel<<<NSITES / 64, 256, 0, stream>>>(In, Weights, bias, G8, Sp);
    gather_kernel<<<NSITES / 64, 256, 0, stream>>>(Sp, G8, NN, out);
}